// Round 11
// baseline (286.651 us; speedup 1.0000x reference)
//
#include <hip/hip_runtime.h>
#include <hip/hip_bf16.h>
#include <stdint.h>

typedef __bf16 bf16x8 __attribute__((ext_vector_type(8)));
typedef float  f32x4  __attribute__((ext_vector_type(4)));

#define MDIM 8192
#define NDIM 4096
#define KDIM 4096
#define BM   256
#define BN   256
#define BK   64
#define NT   (KDIM / BK)   // 64 K-tiles

// ---------------------------------------------------------------- helpers
__device__ __forceinline__ void lds_load16(const void* gsrc, void* ldst) {
    __builtin_amdgcn_global_load_lds(
        (const __attribute__((address_space(1))) unsigned int*)gsrc,
        (__attribute__((address_space(3)))       unsigned int*)ldst,
        16, 0, 0);
}

// ---------------------------------------------------------------- x -> bf16
__global__ __launch_bounds__(256) void cvt_x(const float* __restrict__ X,
                                             __bf16* __restrict__ Xb) {
    size_t t  = (size_t)blockIdx.x * blockDim.x + threadIdx.x;
    size_t i0 = t * 8;
    float4 a = *(const float4*)(X + i0);
    float4 b = *(const float4*)(X + i0 + 4);
    bf16x8 o;
    o[0] = (__bf16)a.x; o[1] = (__bf16)a.y; o[2] = (__bf16)a.z; o[3] = (__bf16)a.w;
    o[4] = (__bf16)b.x; o[5] = (__bf16)b.y; o[6] = (__bf16)b.z; o[7] = (__bf16)b.w;
    *(bf16x8*)(Xb + i0) = o;
}

// ------------------------------------------- Bt[c][k] = d[k]*W[c>>7][k>>7][(k-c)&127]
__global__ __launch_bounds__(256) void build_bt(const float* __restrict__ W,
                                                const float* __restrict__ d,
                                                __bf16* __restrict__ Bt) {
    int t  = blockIdx.x * blockDim.x + threadIdx.x;
    int c  = t >> 9;
    int k0 = (t & 511) * 8;
    int i  = c  >> 7;
    int j  = k0 >> 7;
    const float* wp = W + ((size_t)i * 32 + j) * 128;
    bf16x8 o;
#pragma unroll
    for (int e = 0; e < 8; ++e) {
        int k = k0 + e;
        float v = wp[(k - c) & 127] * d[k];
        o[e] = (__bf16)v;
    }
    *(bf16x8*)(Bt + (size_t)c * KDIM + k0) = o;
}

// ---------------------------------------------------------------- GEMM
// C[M][N] = A[M][K] * Bt[N][K]^T + bias.  256x256 tile, BK=64, 8 waves (2x4),
// 16x16x32 MFMA, 4 single-barrier phases/K-tile.  Identical to r10 EXCEPT:
// all per-phase `asm lgkmcnt(0)` and `s_setprio` scheduling fences are
// REMOVED.  Rationale (r10 post-mortem): per-CU per-K-tile LDS-read demand
// (~2304 cyc) == MFMA demand (~2483 cyc); forced full-drain before each
// MFMA cluster serializes the two pipes (observed MfmaUtil 54% == serial
// sum).  Compiler inserts precise per-use lgkmcnt (m97 evidence), letting
// reads of phase q+1 overlap the MFMA cluster of phase q.
//
// Race safety under consumption-drain: every ds_read issued in phase q is
// data-consumed by MFMA16(q), so the compiler's waits drain it before the
// wave arrives at the NEXT barrier.  Slot audit (stage -> region's last
// reader): ph1 A(t+1) vs A(t)'s... A(t-1) quad3 reads consumed by t-1.ph3
// MFMA (before arrival at t.ph0 barrier); DMA issues after exiting t.ph0
// barrier => happens-after.  ph2/ph3 B(t+2)->buf[par] vs B(t)'s ph0 reads:
// consumed by MFMA16(0) before arrival at t.ph1 barrier; DMA issues after
// exiting t.ph1/ph2 barriers => >=1 full barrier margin.  SAFE.
// vmcnt ledger unchanged from r10: at t.ph3, queue = [B(t+1)4, A(t+1)4,
// B(t+2)4] -> vmcnt(4); tail t>=NT-2 -> vmcnt(0) (round-2/7/8 bug class).
__global__ __launch_bounds__(512, 2) void gemm_bc(const __bf16* __restrict__ A,
                                                  const __bf16* __restrict__ Bt,
                                                  const float* __restrict__ bias,
                                                  float* __restrict__ C) {
    __shared__ __align__(16) char lds[2 * 65536];

    // T1: XCD bijective swizzle (grid = 512, divisible by 8)
    const int bid = blockIdx.x;
    const int cpx = gridDim.x >> 3;
    const int swz = (bid & 7) * cpx + (bid >> 3);
    const int ntn = NDIM / BN;                 // 16
    const int brow = (swz / ntn) * BM;
    const int bcol = (swz % ntn) * BN;

    const int tid  = threadIdx.x;
    const int wid  = tid >> 6;
    const int lane = tid & 63;
    const int wr   = wid >> 2;                 // 0..1 -> A half
    const int wc   = wid & 3;                  // 0..3 -> 64-col panel
    const int rlo  = lane & 15;
    const int kg   = lane >> 4;

    // ds_read addressing (T2 swizzle on the k-offset within each 128B row)
    const int xorK = (rlo & 7) << 4;
    const int kb0  = ((kg * 16)      ^ xorK);
    const int kb1  = ((64 + kg * 16) ^ xorK);
    const char* bufA0 = lds + wr * 16384 + rlo * 128;
    const char* bufB0 = lds + 32768 + (wc >> 1) * 16384 + ((wc & 1) * 64 + rlo) * 128;

    // staging source (pre-swizzled global col so linear LDS dest == swizzled)
    const int sRow = wid * 8 + (lane >> 3);
    const int sCol = 8 * ((lane & 7) ^ ((lane >> 3) & 7));

    const __bf16* Abase = A  + (size_t)brow * KDIM;
    const __bf16* Bbase = Bt + (size_t)bcol * KDIM;

    auto stageA = [&](int t_, int half, int par_) {
#pragma unroll
        for (int l = 0; l < 2; ++l) {
            const __bf16* gp = Abase + (size_t)(half * 128 + l * 64 + sRow) * KDIM
                               + t_ * 64 + sCol;
            lds_load16(gp, lds + par_ * 65536 + half * 16384 + l * 8192 + wid * 1024);
        }
    };
    auto stageB = [&](int t_, int half, int par_) {
#pragma unroll
        for (int l = 0; l < 2; ++l) {
            const __bf16* gp = Bbase + (size_t)(half * 128 + l * 64 + sRow) * KDIM
                               + t_ * 64 + sCol;
            lds_load16(gp, lds + par_ * 65536 + 32768 + half * 16384 + l * 8192 + wid * 1024);
        }
    };

    f32x4 acc[8][4];
#pragma unroll
    for (int i = 0; i < 8; ++i)
#pragma unroll
        for (int j = 0; j < 4; ++j) acc[i][j] = (f32x4)0.0f;

    // prologue: B(0), A(0) -> buf0 ; B(1) (both halves) -> buf1 = 12 loads.
    // vmcnt(4) retires B(0)+A(0), keeps B(1)x4 in flight == induction state.
    stageB(0, 0, 0); stageB(0, 1, 0);
    stageA(0, 0, 0); stageA(0, 1, 0);
    stageB(1, 0, 1); stageB(1, 1, 1);
    asm volatile("s_waitcnt vmcnt(4)" ::: "memory");
    __builtin_amdgcn_s_barrier();

    bf16x8 bf[4][2];   // B fragments, live across the whole K-tile

#define MFMA16(q)                                                                   \
    _Pragma("unroll")                                                               \
    for (int j = 0; j < 4; ++j) {                                                   \
        acc[(q)*2+0][j] = __builtin_amdgcn_mfma_f32_16x16x32_bf16(a00, bf[j][0], acc[(q)*2+0][j], 0, 0, 0); \
        acc[(q)*2+0][j] = __builtin_amdgcn_mfma_f32_16x16x32_bf16(a01, bf[j][1], acc[(q)*2+0][j], 0, 0, 0); \
        acc[(q)*2+1][j] = __builtin_amdgcn_mfma_f32_16x16x32_bf16(a10, bf[j][0], acc[(q)*2+1][j], 0, 0, 0); \
        acc[(q)*2+1][j] = __builtin_amdgcn_mfma_f32_16x16x32_bf16(a11, bf[j][1], acc[(q)*2+1][j], 0, 0, 0); \
    }

#define READ_A(q)                                                                   \
    bf16x8 a00 = *(const bf16x8*)(bufA + (q) * 4096 +    0 + kb0);                  \
    bf16x8 a01 = *(const bf16x8*)(bufA + (q) * 4096 +    0 + kb1);                  \
    bf16x8 a10 = *(const bf16x8*)(bufA + (q) * 4096 + 2048 + kb0);                  \
    bf16x8 a11 = *(const bf16x8*)(bufA + (q) * 4096 + 2048 + kb1);

#pragma unroll 2
    for (int t = 0; t < NT; ++t) {
        const int par = t & 1;
        const char* bufA = bufA0 + par * 65536;
        const char* bufB = bufB0 + par * 65536;

        // ---- phase 0: 8 B-frag reads + A quad0 ; no stage
        {
#pragma unroll
            for (int j = 0; j < 4; ++j) {
                bf[j][0] = *(const bf16x8*)(bufB + j * 2048 + kb0);
                bf[j][1] = *(const bf16x8*)(bufB + j * 2048 + kb1);
            }
            READ_A(0)
            __builtin_amdgcn_s_barrier();
            MFMA16(0)
        }
        // ---- phase 1: A quad1 ; stage A(t+1).lo + A(t+1).hi
        {
            READ_A(1)
            if (t + 1 < NT) { stageA(t + 1, 0, 1 - par); stageA(t + 1, 1, 1 - par); }
            __builtin_amdgcn_s_barrier();
            MFMA16(1)
        }
        // ---- phase 2: A quad2 ; stage B(t+2).lo
        {
            READ_A(2)
            if (t + 2 < NT) stageB(t + 2, 0, par);
            __builtin_amdgcn_s_barrier();
            MFMA16(2)
        }
        // ---- phase 3: A quad3 ; stage B(t+2).hi ; folded boundary vmcnt
        {
            READ_A(3)
            if (t + 2 < NT) stageB(t + 2, 1, par);
            if (t < NT - 2) { asm volatile("s_waitcnt vmcnt(4)" ::: "memory"); }
            else            { asm volatile("s_waitcnt vmcnt(0)" ::: "memory"); }
            __builtin_amdgcn_s_barrier();
            MFMA16(3)
        }
    }
#undef MFMA16
#undef READ_A

    // epilogue: D layout col=lane&15, row=(lane>>4)*4+reg  [m89]
#pragma unroll
    for (int j = 0; j < 4; ++j) {
        const int col = bcol + wc * 64 + j * 16 + rlo;
        const float bs = bias[col];
#pragma unroll
        for (int i = 0; i < 8; ++i) {
            const int row = brow + wr * 128 + i * 16 + kg * 4;
#pragma unroll
            for (int r = 0; r < 4; ++r)
                C[(size_t)(row + r) * NDIM + col] = acc[i][j][r] + bs;
        }
    }
}

// ---------------------------------------------------------------- launch
extern "C" void kernel_launch(void* const* d_in, const int* in_sizes, int n_in,
                              void* d_out, int out_size, void* d_ws, size_t ws_size,
                              hipStream_t stream) {
    const float* x    = (const float*)d_in[0];
    const float* W    = (const float*)d_in[1];
    const float* d    = (const float*)d_in[2];
    const float* bias = (const float*)d_in[3];
    float* y = (float*)d_out;

    __bf16* Xb = (__bf16*)d_ws;                                    // 64 MiB
    __bf16* Bt = (__bf16*)((char*)d_ws + (size_t)MDIM * KDIM * 2); // 32 MiB

    cvt_x<<<(MDIM * (size_t)KDIM) / 8 / 256, 256, 0, stream>>>(x, Xb);
    build_bt<<<(NDIM * KDIM) / 8 / 256, 256, 0, stream>>>(W, d, Bt);
    gemm_bc<<<(MDIM / BM) * (NDIM / BN), 512, 0, stream>>>(Xb, Bt, bias, y);
}